// Round 4
// baseline (437.862 us; speedup 1.0000x reference)
//
#include <hip/hip_runtime.h>

#define EPS 1e-6f

// Direct HW transcendentals (v_exp_f32 = 2^x, v_log_f32 = log2 x).
// NOTE: do NOT use __exp2f/__log2f — they collide with glibc math.h macros
// in this harness's host compile pass (round-3 compile failure).
__device__ __forceinline__ float hw_exp2(float x) { return __builtin_amdgcn_exp2f(x); }
__device__ __forceinline__ float hw_log2(float x) { return __builtin_amdgcn_logf(x); }

constexpr int T_LEN  = 4000;
constexpr int N_ROWS = 128 * 128;   // 16384 independent (B,F) rows
constexpr int CHUNK  = 256;         // elements per wave per chunk (64 lanes x float4)
constexpr int NCHUNK = (T_LEN + CHUNK - 1) / CHUNK;  // 16 (last chunk = 160 elems)

__global__ __launch_bounds__(256)
void pcen_kernel(const float* __restrict__ x,
                 const float* __restrict__ alpha_p,
                 const float* __restrict__ delta_p,
                 const float* __restrict__ r_p,
                 float* __restrict__ out)
{
    const int wave = (blockIdx.x * blockDim.x + threadIdx.x) >> 6;  // row id
    const int lane = threadIdx.x & 63;
    if (wave >= N_ROWS) return;

    const float* __restrict__ xr   = x   + (long long)wave * T_LEN;
    float*       __restrict__ orow = out + (long long)wave * T_LEN;

    // ---- compile-time recurrence constants (match Python: S = 512/(22050*0.06)) ----
    const double s_d = 512.0 / (22050.0 * 0.06);
    const double a_d = 1.0 - s_d;
    const float  s   = (float)s_d;
    const float  a   = (float)a_d;
    const double q_d  = a_d * a_d * a_d * a_d;     // a^4 : per-lane-segment decay
    const double q2d  = q_d  * q_d;
    const double q4d  = q2d  * q2d;
    const double q8d  = q4d  * q4d;
    const double q16d = q8d  * q8d;
    const float q1  = (float)q_d;
    const float q2  = (float)q2d;
    const float q4  = (float)q4d;
    const float q8  = (float)q8d;
    const float q16 = (float)q16d;                 // a^64  ~ 2.6e-14
    const float q32 = (float)(q16d * q16d);        // a^128 ~ 6.6e-28 (still normal f32)

    // q^lane (binary exponentiation in double, once per thread)
    double pl = 1.0, bb = q_d;
    int e = lane;
    while (e) { if (e & 1) pl *= bb; bb *= bb; e >>= 1; }
    const float qlane = (float)pl;   // underflows to 0 for large lane — contribution negligible anyway

    // ---- scalar params (broadcast loads) ----
    const float alpha = fminf(fmaxf(alpha_p[0], 0.01f), 0.99f);
    const float delta = fabsf(delta_p[0]) + EPS;
    const float rr    = fminf(fmaxf(r_p[0], 0.01f), 1.0f);
    const float delta_r = hw_exp2(rr * hw_log2(delta));

    float C = 0.0f;   // running carry: M[t-1] entering current chunk

    for (int c = 0; c < NCHUNK; ++c) {
        const int base = c * CHUNK + lane * 4;
        const bool valid = (base + 3) < T_LEN;   // T_LEN % 4 == 0, so all-or-nothing

        float4 xv = make_float4(0.f, 0.f, 0.f, 0.f);
        if (valid) xv = *reinterpret_cast<const float4*>(xr + base);

        // first element of the whole row: M[0] = x[0] (weight 1, not s)
        const float w0 = (c == 0 && lane == 0) ? 1.0f : s;

        // per-lane affine segment: carry_out = a^4 * carry_in + B3
        const float B0 = w0 * xv.x;
        const float B1 = fmaf(a, B0, s * xv.y);
        const float B2 = fmaf(a, B1, s * xv.z);
        const float B3 = fmaf(a, B2, s * xv.w);

        // inclusive Kogge-Stone scan of B3 across lanes with ratio q = a^4:
        // p_j = sum_{i<=j} q^{j-i} * B3_i
        float p = B3, up;
        up = __shfl_up(p, 1);  if (lane >= 1)  p = fmaf(q1,  up, p);
        up = __shfl_up(p, 2);  if (lane >= 2)  p = fmaf(q2,  up, p);
        up = __shfl_up(p, 4);  if (lane >= 4)  p = fmaf(q4,  up, p);
        up = __shfl_up(p, 8);  if (lane >= 8)  p = fmaf(q8,  up, p);
        up = __shfl_up(p, 16); if (lane >= 16) p = fmaf(q16, up, p);
        up = __shfl_up(p, 32); if (lane >= 32) p = fmaf(q32, up, p);

        // carry entering this lane's segment: q^lane * C + P_{lane-1}
        const float pm = __shfl_up(p, 1);
        const float carry_in = (lane == 0) ? C : fmaf(qlane, C, pm);

        // reconstruct the 4 M values sequentially
        const float m0 = fmaf(a, carry_in, B0);  // == a*carry_in + w0*x0
        const float m1 = fmaf(a, m0, s * xv.y);
        const float m2 = fmaf(a, m1, s * xv.z);
        const float m3 = fmaf(a, m2, s * xv.w);

        // next chunk carry = M at last element of lane 63 (a^256*C term underflows; negligible)
        C = __shfl(p, 63);

        if (valid) {
            // out = (x * (EPS+M)^(-alpha) + delta)^r - delta^r
            float4 ov;
            {
                const float inv_s = hw_exp2(-alpha * hw_log2(EPS + m0));
                ov.x = hw_exp2(rr * hw_log2(fmaf(xv.x, inv_s, delta))) - delta_r;
            }
            {
                const float inv_s = hw_exp2(-alpha * hw_log2(EPS + m1));
                ov.y = hw_exp2(rr * hw_log2(fmaf(xv.y, inv_s, delta))) - delta_r;
            }
            {
                const float inv_s = hw_exp2(-alpha * hw_log2(EPS + m2));
                ov.z = hw_exp2(rr * hw_log2(fmaf(xv.z, inv_s, delta))) - delta_r;
            }
            {
                const float inv_s = hw_exp2(-alpha * hw_log2(EPS + m3));
                ov.w = hw_exp2(rr * hw_log2(fmaf(xv.w, inv_s, delta))) - delta_r;
            }
            *reinterpret_cast<float4*>(orow + base) = ov;
        }
    }
}

extern "C" void kernel_launch(void* const* d_in, const int* in_sizes, int n_in,
                              void* d_out, int out_size, void* d_ws, size_t ws_size,
                              hipStream_t stream) {
    const float* x       = (const float*)d_in[0];
    const float* alpha_p = (const float*)d_in[1];
    const float* delta_p = (const float*)d_in[2];
    const float* r_p     = (const float*)d_in[3];
    float* out = (float*)d_out;

    // one wave per row, 4 waves per block -> 4096 blocks
    const int blocks = N_ROWS / 4;
    pcen_kernel<<<blocks, 256, 0, stream>>>(x, alpha_p, delta_p, r_p, out);
}